// Round 7
// baseline (1015.443 us; speedup 1.0000x reference)
//
#include <hip/hip_runtime.h>
#include <math.h>

#define B_ROWS 4096
#define DIM    1024
#define NTOT   8192
#define NCLS   40
#define TILES2 32          // 8192 / 256
#define NGRAM  528         // 32*33/2 upper-tri 256^2 tiles
#define NNLL   8           // 4096 / 512
#define NMATD  512         // 4096 / 8 (8 waves/block, 1 item/wave)
#define NMAIN  (NGRAM + NNLL + NMATD)   // 1048

typedef __attribute__((ext_vector_type(8))) short bf16x8;
typedef __attribute__((ext_vector_type(4))) float f32x4;

// ws layout (floats): [0]=nll_sum [1]=matdiff_sum [2]=sum_sq [3]=sxx [4]=syy
// [5]=smix(xy+yx) [6]=unused [7]=ticket ; [8..1032)=colsum[1024] ;
// [1032..9224)=sq[8192] ; byte 36896+ : bf16 total[8192*1024]
#define WS_TOT_BYTE_OFF 36896

#define MFMA16(d, x, y) d = __builtin_amdgcn_mfma_f32_16x16x32_bf16(x, y, d, 0, 0, 0)

__device__ __forceinline__ unsigned short f2bf(float f) {
  unsigned int u = __float_as_uint(f);
  u += 0x7fffu + ((u >> 16) & 1u);   // RNE
  return (unsigned short)(u >> 16);
}

__device__ __forceinline__ void async16(const void* g, void* l) {
  __builtin_amdgcn_global_load_lds(
      (const __attribute__((address_space(1))) unsigned int*)g,
      (__attribute__((address_space(3))) unsigned int*)l, 16, 0, 0);
}

__device__ __forceinline__ float wave_sum(float v) {
  v += __shfl_xor(v, 32);
  v += __shfl_xor(v, 16);
  v += __shfl_xor(v, 8);
  v += __shfl_xor(v, 4);
  v += __shfl_xor(v, 2);
  v += __shfl_xor(v, 1);
  return v;
}

__global__ void init_k(float* W) {
  int t = blockIdx.x * blockDim.x + threadIdx.x;
  if (t < 1032) W[t] = 0.f;   // scalars + ticket + colsum
}

// ---------------- prep: 256 blocks x 256 threads (unchanged r6 version) ------
__global__ __launch_bounds__(256) void prep_k(const float* __restrict__ dense,
                                              const float* __restrict__ sparse,
                                              float* __restrict__ W,
                                              unsigned short* __restrict__ tot) {
  float* colsum = W + 8;
  float* sq = W + 1032;
  const int t = threadIdx.x;
  const int lane = t & 63, wave = t >> 6;
  __shared__ float colsum_l[1024];
  __shared__ float w2r[4];
  #pragma unroll
  for (int x = 0; x < 4; ++x) colsum_l[t * 4 + x] = 0.f;

  float c[4][4];
  #pragma unroll
  for (int j = 0; j < 4; ++j)
    #pragma unroll
    for (int x = 0; x < 4; ++x) c[j][x] = 0.f;

  float rowtot = 0.f;
  const int rbase = blockIdx.x * 32 + wave;   // 8 rows per wave, stride 4
  for (int i = 0; i < 8; ++i) {
    const int r = rbase + i * 4;
    const float* src = (r < B_ROWS) ? dense + (size_t)r * DIM
                                    : sparse + (size_t)(r - B_ROWS) * DIM;
    float sp = 0.f;
    #pragma unroll
    for (int j = 0; j < 4; ++j) {
      float4 v = ((const float4*)src)[lane + 64 * j];
      c[j][0] += v.x; c[j][1] += v.y; c[j][2] += v.z; c[j][3] += v.w;
      sp += v.x * v.x + v.y * v.y + v.z * v.z + v.w * v.w;
      ushort4 o;
      o.x = f2bf(v.x); o.y = f2bf(v.y); o.z = f2bf(v.z); o.w = f2bf(v.w);
      *(ushort4*)(tot + (size_t)r * DIM + (lane + 64 * j) * 4) = o;
    }
    sp = wave_sum(sp);
    if (lane == 0) { sq[r] = sp; rowtot += sp; }
  }
  if (lane == 0) w2r[wave] = rowtot;

  __syncthreads();
  #pragma unroll
  for (int j = 0; j < 4; ++j)
    #pragma unroll
    for (int x = 0; x < 4; ++x)
      atomicAdd(&colsum_l[4 * lane + 256 * j + x], c[j][x]);
  __syncthreads();
  #pragma unroll
  for (int x = 0; x < 4; ++x)
    atomicAdd(&colsum[t * 4 + x], colsum_l[t * 4 + x]);
  if (t == 0) atomicAdd(&W[2], w2r[0] + w2r[1] + w2r[2] + w2r[3]);
}

// ---------------- fused main: gram (528) + nll (8) + matdiff (512), 512 thr --

struct SmemMain {
  short A[2][8192];   // [buf][256 rows x 32 k] = 16KB per plane
  short B[2][8192];
  float sqA[256], sqB[256];
  float red[8];
};

// gram: 256x256 tiles, 8 waves (2Mx4N), BK=32, ring-2 LDS (68KB -> target
// 2 blocks/CU; acc in AGPRs keeps arch VGPR ~104 per r5).  Counted pipeline:
// during tile kt stage tile kt+2 into the buffer kt just vacated; per tile:
// ds_reads ; lgkmcnt(0) ; barrier (all reads landed) ; stage ; MFMA(setprio) ;
// vmcnt(4) (retire tile kt+1 only — never 0 until tail) ; barrier.
// Cross-block overlap (m114) supplies the latency hiding 1-block lockstep
// lacked in r2/r3/r5.  Swizzle identical to r5 (verified 0 conflicts).
__device__ void gram_body(int bid, const unsigned short* __restrict__ tot,
                          float* __restrict__ W, SmemMain& sm) {
  const float* sq = W + 1032;
  const float* colsum = W + 8;
  const int t = threadIdx.x;              // 0..511
  const int lane = t & 63, wave = t >> 6; // 8 waves
  const int wr = wave >> 2, wc = wave & 3;

  // T1: XCD-contiguous remap; 528 = 8*66 -> chunking bijective
  int p = (bid & 7) * (NGRAM / 8) + (bid >> 3);

  // decode linear id -> (bi, bj), bi <= bj, T=32
  int bi = (int)((2 * TILES2 + 1 -
                  sqrtf((float)((2 * TILES2 + 1) * (2 * TILES2 + 1) - 8 * p))) * 0.5f);
  if (bi < 0) bi = 0;
  if (bi >= TILES2) bi = TILES2 - 1;
  int start = bi * (2 * TILES2 - bi + 1) / 2;
  while (p < start) { --bi; start = bi * (2 * TILES2 - bi + 1) / 2; }
  while (p >= start + (TILES2 - bi)) { start += TILES2 - bi; ++bi; }
  const int bj = bi + (p - start);

  // staging: chunks c0 = t (rows 0-127), c1 = 512+t (rows 128-255);
  // row = c>>2, slot_l = c&3, global seg = slot_l ^ ((row>>1)&3)
  const int r0 = t >> 2;
  const int sg = (t & 3) ^ ((r0 >> 1) & 3);
  const unsigned short* gA0 = tot + (size_t)(bi * 256 + r0) * DIM + sg * 8;
  const unsigned short* gA1 = gA0 + (size_t)128 * DIM;
  const unsigned short* gB0 = tot + (size_t)(bj * 256 + r0) * DIM + sg * 8;
  const unsigned short* gB1 = gB0 + (size_t)128 * DIM;
  const int ldo0 = t * 8, ldo1 = t * 8 + 4096;   // shorts within plane

  auto stage = [&](int kt, short* sa, short* sb) {
    const size_t ko = (size_t)kt * 32;
    async16(gA0 + ko, sa + ldo0);
    async16(gA1 + ko, sa + ldo1);
    async16(gB0 + ko, sb + ldo0);
    async16(gB1 + ko, sb + ldo1);
  };

  // prologue: stage tiles 0,1 (8 loads in flight)
  stage(0, sm.A[0], sm.B[0]);
  stage(1, sm.A[1], sm.B[1]);

  // overlap with load latency: sq staging + per-block bandwidth coefficient
  if (t < 256) sm.sqA[t] = sq[bi * 256 + t];
  else         sm.sqB[t - 256] = sq[bj * 256 + (t - 256)];
  float csp = 0.f;
  #pragma unroll
  for (int j = 0; j < 16; ++j) { float v = colsum[lane + 64 * j]; csp += v * v; }
  csp = wave_sum(csp);
  double sumdots = (double)csp;
  double sum_sq = (double)W[2];
  double sumL2 = 2.0 * (double)NTOT * sum_sq - 2.0 * sumdots;
  double bwv = sumL2 / ((double)NTOT * (double)NTOT - (double)NTOT);
  const float cexp16 = (float)(4.0 / bwv) * 0.0625f;  // c/16: widest kernel coeff

  f32x4 acc[8][4];
  #pragma unroll
  for (int m = 0; m < 8; ++m)
    #pragma unroll
    for (int n = 0; n < 4; ++n) acc[m][n] = (f32x4)(0.f);

  // ds_read addressing: row*64B + ((q ^ ((fr>>1)&3))<<4); fragment-row bases
  // are multiples of 16 so (row>>1)&3 == (fr>>1)&3  (r5-verified, 0 conflicts)
  const int q = lane >> 4;
  const int fr = lane & 15;
  const int rb = (q ^ ((fr >> 1) & 3)) << 4;
  const int aoff = (wr * 128 + fr) * 64 + rb;   // + m*1024 per m-frag
  const int boff = (wc * 64 + fr) * 64 + rb;    // + n*1024 per n-frag

  // tile 0 landed (tile 1's 4 newest loads stay in flight; the colsum global
  // reads above were drained by the compiler's own waits already)
  asm volatile("s_waitcnt vmcnt(4)" ::: "memory");
  __builtin_amdgcn_s_barrier();

  short* cA = sm.A[0]; short* cB = sm.B[0];
  short* nA = sm.A[1]; short* nB = sm.B[1];

  for (int kt = 0; kt < 32; ++kt) {
    bf16x8 a[8], b[4];
    #pragma unroll
    for (int m = 0; m < 8; ++m)
      a[m] = *(const bf16x8*)((const char*)cA + aoff + m * 1024);
    #pragma unroll
    for (int n = 0; n < 4; ++n)
      b[n] = *(const bf16x8*)((const char*)cB + boff + n * 1024);
    // own frag data in regs, then all waves' reads done -> safe to overwrite
    asm volatile("s_waitcnt lgkmcnt(0)" ::: "memory");
    __builtin_amdgcn_s_barrier();
    if (kt < 30) stage(kt + 2, cA, cB);   // reuse the buffer just vacated
    __builtin_amdgcn_s_setprio(1);
    #pragma unroll
    for (int m = 0; m < 8; ++m)
      #pragma unroll
      for (int n = 0; n < 4; ++n) MFMA16(acc[m][n], a[m], b[n]);
    __builtin_amdgcn_s_setprio(0);
    // retire exactly tile kt+1 (kt+2's 4 loads stay in flight)
    if (kt < 30)       { asm volatile("s_waitcnt vmcnt(4)" ::: "memory"); }
    else if (kt == 30) { asm volatile("s_waitcnt vmcnt(0)" ::: "memory"); }
    if (kt < 31) __builtin_amdgcn_s_barrier();
    short* ta = cA; cA = nA; nA = ta;
    short* tb = cB; cB = nB; nB = tb;
  }

  // epilogue: l2 -> 5-kernel sum. k_i = exp(-l2*c/2^i); exp of smallest,
  // then 4 squarings
  float s = 0.f;
  const int crow = (lane >> 4) * 4;
  #pragma unroll
  for (int m = 0; m < 8; ++m) {
    #pragma unroll
    for (int n = 0; n < 4; ++n) {
      #pragma unroll
      for (int r = 0; r < 4; ++r) {
        int il = wr * 128 + 16 * m + crow + r;
        int jl = wc * 64 + 16 * n + fr;
        float l2 = sm.sqA[il] + sm.sqB[jl] - 2.f * acc[m][n][r];
        l2 = fmaxf(l2, 0.f);
        float k4 = __expf(-l2 * cexp16);
        float k3 = k4 * k4;
        float k2 = k3 * k3;
        float k1 = k2 * k2;
        float k0 = k1 * k1;
        s += k0 + k1 + k2 + k3 + k4;
      }
    }
  }
  s = wave_sum(s);
  if (lane == 0) sm.red[wave] = s;
  __syncthreads();
  if (t == 0) {
    float ts = 0.f;
    #pragma unroll
    for (int w = 0; w < 8; ++w) ts += sm.red[w];
    int idx; float wgt;
    if (bi == bj)      { idx = (bi < 16) ? 3 : 4; wgt = 1.f; }
    else if (bj < 16)  { idx = 3; wgt = 2.f; }
    else if (bi >= 16) { idx = 4; wgt = 2.f; }
    else               { idx = 5; wgt = 2.f; }
    atomicAdd(&W[idx], wgt * ts);
  }
}

__device__ void nll_body(int bid, const float* __restrict__ pred,
                         const int* __restrict__ tgt, float* __restrict__ W,
                         SmemMain& sm) {
  const int t = threadIdx.x;
  const int i = bid * 512 + t;
  float v = pred[(size_t)i * NCLS + tgt[i]];
  v = wave_sum(v);
  if ((t & 63) == 0) sm.red[t >> 6] = v;
  __syncthreads();
  if (t == 0) {
    float s = 0.f;
    #pragma unroll
    for (int w = 0; w < 8; ++w) s += sm.red[w];
    atomicAdd(&W[0], s);
  }
}

__device__ void matdiff_body(int bid, const float* __restrict__ trans,
                             float* __restrict__ W, SmemMain& sm) {
  const int t = threadIdx.x;
  const int lane = t & 63, wave = t >> 6;
  const int b = bid * 8 + wave;           // 1 item per wave, 8 waves
  const float* Tb = trans + (size_t)b * 4096;
  const int fr = lane & 15;
  const int k8 = (lane >> 4) * 8;
  bf16x8 frag[4][2];
  #pragma unroll
  for (int m = 0; m < 4; ++m) {
    #pragma unroll
    for (int kk = 0; kk < 2; ++kk) {
      const float* p = Tb + (size_t)(16 * m + fr) * 64 + kk * 32 + k8;
      float4 u0 = *(const float4*)p;
      float4 u1 = *(const float4*)(p + 4);
      bf16x8 f;
      f[0] = (short)f2bf(u0.x); f[1] = (short)f2bf(u0.y);
      f[2] = (short)f2bf(u0.z); f[3] = (short)f2bf(u0.w);
      f[4] = (short)f2bf(u1.x); f[5] = (short)f2bf(u1.y);
      f[6] = (short)f2bf(u1.z); f[7] = (short)f2bf(u1.w);
      frag[m][kk] = f;
    }
  }
  f32x4 acc[4][4];
  #pragma unroll
  for (int m = 0; m < 4; ++m)
    #pragma unroll
    for (int n = 0; n < 4; ++n) acc[m][n] = (f32x4)(0.f);
  #pragma unroll
  for (int kk = 0; kk < 2; ++kk)
    #pragma unroll
    for (int m = 0; m < 4; ++m)
      #pragma unroll
      for (int n = 0; n < 4; ++n)
        acc[m][n] = __builtin_amdgcn_mfma_f32_16x16x32_bf16(frag[m][kk], frag[n][kk],
                                                            acc[m][n], 0, 0, 0);
  float s = 0.f;
  const int crow = (lane >> 4) * 4;
  #pragma unroll
  for (int m = 0; m < 4; ++m)
    #pragma unroll
    for (int n = 0; n < 4; ++n)
      #pragma unroll
      for (int r = 0; r < 4; ++r) {
        int grow = 16 * m + crow + r;
        int gcol = 16 * n + fr;
        float g = acc[m][n][r];
        float d = (grow == gcol) ? (1.f - g) : (-g);
        s += d * d;
      }
  s = wave_sum(s);
  if (lane == 0) sm.red[wave] = sqrtf(s);
  __syncthreads();
  if (t == 0) {
    float s8 = 0.f;
    #pragma unroll
    for (int w = 0; w < 8; ++w) s8 += sm.red[w];
    atomicAdd(&W[1], s8);
  }
}

__global__ __launch_bounds__(512, 4) void fused_main_k(
    const float* __restrict__ pred, const int* __restrict__ tgt,
    const float* __restrict__ trans, const unsigned short* __restrict__ tot,
    float* __restrict__ W, float* __restrict__ out) {
  __shared__ SmemMain sm;
  const int blk = blockIdx.x;
  if (blk < NGRAM)             gram_body(blk, tot, W, sm);
  else if (blk < NGRAM + NNLL) nll_body(blk - NGRAM, pred, tgt, W, sm);
  else                         matdiff_body(blk - NGRAM - NNLL, trans, W, sm);

  // ticket: last of all NMAIN blocks does the final combine
  if (threadIdx.x == 0) {
    __threadfence();
    unsigned int tk = atomicAdd((unsigned int*)(W + 7), 1u);
    if (tk == NMAIN - 1) {
      __threadfence();
      float nll = -*(volatile float*)(W + 0) / (float)B_ROWS;
      float mat =  *(volatile float*)(W + 1) / (float)B_ROWS;
      float sxx =  *(volatile float*)(W + 3);
      float syy =  *(volatile float*)(W + 4);
      float smx =  *(volatile float*)(W + 5);
      float mmd = (sxx + syy - smx) / ((float)B_ROWS * (float)B_ROWS);
      out[0] = 0.1f * nll + 0.001f * mat + 0.5f * mmd;
    }
  }
}

extern "C" void kernel_launch(void* const* d_in, const int* in_sizes, int n_in,
                              void* d_out, int out_size, void* d_ws, size_t ws_size,
                              hipStream_t stream) {
  const float* pred   = (const float*)d_in[0];
  const int*   tgt    = (const int*)d_in[1];
  const float* trans  = (const float*)d_in[2];
  const float* dense  = (const float*)d_in[3];
  const float* sparse = (const float*)d_in[4];
  float* W = (float*)d_ws;
  unsigned short* tot = (unsigned short*)((char*)d_ws + WS_TOT_BYTE_OFF);
  float* out = (float*)d_out;

  init_k<<<dim3(5), dim3(256), 0, stream>>>(W);
  prep_k<<<dim3(256), dim3(256), 0, stream>>>(dense, sparse, W, tot);
  fused_main_k<<<dim3(NMAIN), dim3(512), 0, stream>>>(pred, tgt, trans, tot, W, out);
}

// Round 8
// 403.116 us; speedup vs baseline: 2.5190x; 2.5190x over previous
//
#include <hip/hip_runtime.h>
#include <math.h>

#define B_ROWS 4096
#define DIM    1024
#define NTOT   8192
#define NCLS   40
#define TILESG 64          // 8192 / 128
#define NGRAM  2080        // 64*65/2 upper-tri 128^2 tiles
#define NNLL   16          // 4096 / 256
#define NMATD  1024        // 4096 / 4 (4 waves/block, 1 item/wave)
#define NMAIN  (NGRAM + NNLL + NMATD)   // 3120

typedef __attribute__((ext_vector_type(8))) short bf16x8;
typedef __attribute__((ext_vector_type(4))) float f32x4;

// ws layout (floats): [0]=nll_sum [1]=matdiff_sum [2]=sum_sq [3]=sxx [4]=syy
// [5]=smix(xy+yx) [6]=unused [7]=ticket ; [8..1032)=colsum[1024] ;
// [1032..9224)=sq[8192] ; byte 36896+ : bf16 total[8192*1024]
#define WS_TOT_BYTE_OFF 36896

#define MFMA16(d, x, y) d = __builtin_amdgcn_mfma_f32_16x16x32_bf16(x, y, d, 0, 0, 0)

__device__ __forceinline__ unsigned short f2bf(float f) {
  unsigned int u = __float_as_uint(f);
  u += 0x7fffu + ((u >> 16) & 1u);   // RNE
  return (unsigned short)(u >> 16);
}

__device__ __forceinline__ void async16(const void* g, void* l) {
  __builtin_amdgcn_global_load_lds(
      (const __attribute__((address_space(1))) unsigned int*)g,
      (__attribute__((address_space(3))) unsigned int*)l, 16, 0, 0);
}

__device__ __forceinline__ float wave_sum(float v) {
  v += __shfl_xor(v, 32);
  v += __shfl_xor(v, 16);
  v += __shfl_xor(v, 8);
  v += __shfl_xor(v, 4);
  v += __shfl_xor(v, 2);
  v += __shfl_xor(v, 1);
  return v;
}

__global__ void init_k(float* W) {
  int t = blockIdx.x * blockDim.x + threadIdx.x;
  if (t < 1032) W[t] = 0.f;   // scalars + ticket + colsum
}

// ---------------- prep: 512 blocks x 256 threads (16 rows/block) -------------
__global__ __launch_bounds__(256) void prep_k(const float* __restrict__ dense,
                                              const float* __restrict__ sparse,
                                              float* __restrict__ W,
                                              unsigned short* __restrict__ tot) {
  float* colsum = W + 8;
  float* sq = W + 1032;
  const int t = threadIdx.x;
  const int lane = t & 63, wave = t >> 6;
  __shared__ float colsum_l[1024];
  __shared__ float w2r[4];
  #pragma unroll
  for (int x = 0; x < 4; ++x) colsum_l[t * 4 + x] = 0.f;

  float c[4][4];
  #pragma unroll
  for (int j = 0; j < 4; ++j)
    #pragma unroll
    for (int x = 0; x < 4; ++x) c[j][x] = 0.f;

  float rowtot = 0.f;
  const int rbase = blockIdx.x * 16 + wave;   // 4 rows per wave, stride 4
  for (int i = 0; i < 4; ++i) {
    const int r = rbase + i * 4;
    const float* src = (r < B_ROWS) ? dense + (size_t)r * DIM
                                    : sparse + (size_t)(r - B_ROWS) * DIM;
    float sp = 0.f;
    #pragma unroll
    for (int j = 0; j < 4; ++j) {
      float4 v = ((const float4*)src)[lane + 64 * j];
      c[j][0] += v.x; c[j][1] += v.y; c[j][2] += v.z; c[j][3] += v.w;
      sp += v.x * v.x + v.y * v.y + v.z * v.z + v.w * v.w;
      ushort4 o;
      o.x = f2bf(v.x); o.y = f2bf(v.y); o.z = f2bf(v.z); o.w = f2bf(v.w);
      *(ushort4*)(tot + (size_t)r * DIM + (lane + 64 * j) * 4) = o;
    }
    sp = wave_sum(sp);
    if (lane == 0) { sq[r] = sp; rowtot += sp; }
  }
  if (lane == 0) w2r[wave] = rowtot;

  __syncthreads();
  #pragma unroll
  for (int j = 0; j < 4; ++j)
    #pragma unroll
    for (int x = 0; x < 4; ++x)
      atomicAdd(&colsum_l[4 * lane + 256 * j + x], c[j][x]);
  __syncthreads();
  #pragma unroll
  for (int x = 0; x < 4; ++x)
    atomicAdd(&colsum[t * 4 + x], colsum_l[t * 4 + x]);
  if (t == 0) atomicAdd(&W[2], w2r[0] + w2r[1] + w2r[2] + w2r[3]);
}

// ---------------- fused main: gram (2080) + nll (16) + matdiff (1024) --------

struct SmemMain {
  short A[2][4096];   // [buf][128 rows x 32 k] = 8KB per plane
  short B[2][4096];
  float sqA[128], sqB[128];
  float red[4];
};

// gram: m97-replica.  128x128 tile, 4 waves (2Mx2N), BK=32, double-buffered
// LDS (32KB), plain __syncthreads only (ONE per K-step), NO inline asm, NO
// setprio.  Latency hiding = 3 co-resident blocks/CU (launch_bounds(256,3)
// caps unified VGPR+AGPR at ~170; body needs ~150) overlapping each other's
// stage/compute (m114).  Per K-step per wave: 8 ds_read_b128 + 4
// global_load_lds_dwordx4 + 16 MFMA — m97's exact histogram.  Swizzle (64B
// rows): seg' = slot ^ ((row>>1)&3) at global source, rb = (q^((fr>>1)&3))<<4
// on read (rule #21; r5-verified 0 conflicts, absmax 0).
__device__ void gram_body(int bid, const unsigned short* __restrict__ tot,
                          float* __restrict__ W, SmemMain& sm) {
  const float* sq = W + 1032;
  const float* colsum = W + 8;
  const int t = threadIdx.x;              // 0..255
  const int lane = t & 63, wave = t >> 6; // 4 waves
  const int wr = wave >> 1, wc = wave & 1;

  // T1: XCD-contiguous remap; 2080 = 8*260 -> chunking bijective
  int p = (bid & 7) * (NGRAM / 8) + (bid >> 3);

  // decode linear id -> (bi, bj), bi <= bj, T=64
  int bi = (int)((2 * TILESG + 1 -
                  sqrtf((float)((2 * TILESG + 1) * (2 * TILESG + 1) - 8 * p))) * 0.5f);
  if (bi < 0) bi = 0;
  if (bi >= TILESG) bi = TILESG - 1;
  int start = bi * (2 * TILESG - bi + 1) / 2;
  while (p < start) { --bi; start = bi * (2 * TILESG - bi + 1) / 2; }
  while (p >= start + (TILESG - bi)) { start += TILESG - bi; ++bi; }
  const int bj = bi + (p - start);

  // staging: chunks c0 = t (rows 0-63), c1 = 256+t (rows 64-127);
  // row = c>>2, slot = c&3, global seg = slot ^ ((row>>1)&3)
  // (identical for both chunks: row1 = row0 + 64, 64 ≡ 0 mod 4 after >>1)
  const int r0 = t >> 2;
  const int sg = (t & 3) ^ ((r0 >> 1) & 3);
  const unsigned short* gA0 = tot + (size_t)(bi * 128 + r0) * DIM + sg * 8;
  const unsigned short* gA1 = gA0 + (size_t)64 * DIM;
  const unsigned short* gB0 = tot + (size_t)(bj * 128 + r0) * DIM + sg * 8;
  const unsigned short* gB1 = gB0 + (size_t)64 * DIM;
  const int ldo0 = t * 8, ldo1 = t * 8 + 2048;   // shorts within plane

  auto stage = [&](int kt, short* sa, short* sb) {
    const size_t ko = (size_t)kt * 32;
    async16(gA0 + ko, sa + ldo0);
    async16(gA1 + ko, sa + ldo1);
    async16(gB0 + ko, sb + ldo0);
    async16(gB1 + ko, sb + ldo1);
  };

  // prologue: stage tile 0 into buffer 0
  stage(0, sm.A[0], sm.B[0]);

  // overlap with load latency: sq staging + per-block bandwidth coefficient
  if (t < 128) sm.sqA[t] = sq[bi * 128 + t];
  else         sm.sqB[t - 128] = sq[bj * 128 + (t - 128)];
  float csp = 0.f;
  #pragma unroll
  for (int j = 0; j < 16; ++j) { float v = colsum[lane + 64 * j]; csp += v * v; }
  csp = wave_sum(csp);
  double sumdots = (double)csp;
  double sum_sq = (double)W[2];
  double sumL2 = 2.0 * (double)NTOT * sum_sq - 2.0 * sumdots;
  double bwv = sumL2 / ((double)NTOT * (double)NTOT - (double)NTOT);
  const float cexp16 = (float)(4.0 / bwv) * 0.0625f;  // c/16: widest kernel coeff

  f32x4 acc[4][4];
  #pragma unroll
  for (int m = 0; m < 4; ++m)
    #pragma unroll
    for (int n = 0; n < 4; ++n) acc[m][n] = (f32x4)(0.f);

  // ds_read addressing: row*64B + ((q ^ ((fr>>1)&3))<<4); fragment-row bases
  // (wr*64, 16m) are multiples of 16 so (row>>1)&3 == (fr>>1)&3
  const int q = lane >> 4;
  const int fr = lane & 15;
  const int rb = (q ^ ((fr >> 1) & 3)) << 4;
  const int aoff = (wr * 64 + fr) * 64 + rb;   // + m*1024 bytes per m-frag
  const int boff = (wc * 64 + fr) * 64 + rb;   // + n*1024 bytes per n-frag

  __syncthreads();   // compiler drains vmcnt: tile 0 in LDS

  short* cA = sm.A[0]; short* cB = sm.B[0];
  short* nA = sm.A[1]; short* nB = sm.B[1];

  for (int kt = 0; kt < 32; ++kt) {
    // issue next-tile stage FIRST (flies under this tile's reads + MFMA);
    // nA/nB were last read at kt-1, barrier already passed -> safe
    if (kt < 31) stage(kt + 1, nA, nB);
    bf16x8 a[4], b[4];
    #pragma unroll
    for (int m = 0; m < 4; ++m)
      a[m] = *(const bf16x8*)((const char*)cA + aoff + m * 1024);
    #pragma unroll
    for (int n = 0; n < 4; ++n)
      b[n] = *(const bf16x8*)((const char*)cB + boff + n * 1024);
    #pragma unroll
    for (int m = 0; m < 4; ++m)
      #pragma unroll
      for (int n = 0; n < 4; ++n) MFMA16(acc[m][n], a[m], b[n]);
    __syncthreads();   // single barrier/K-step: drains stage, retires reads
    short* ta = cA; cA = nA; nA = ta;
    short* tb = cB; cB = nB; nB = tb;
  }

  // epilogue: l2 -> 5-kernel sum. k_i = exp(-l2*c/2^i); exp of smallest,
  // then 4 squarings
  float s = 0.f;
  const int crow = (lane >> 4) * 4;
  #pragma unroll
  for (int m = 0; m < 4; ++m) {
    #pragma unroll
    for (int n = 0; n < 4; ++n) {
      #pragma unroll
      for (int r = 0; r < 4; ++r) {
        int il = wr * 64 + 16 * m + crow + r;
        int jl = wc * 64 + 16 * n + fr;
        float l2 = sm.sqA[il] + sm.sqB[jl] - 2.f * acc[m][n][r];
        l2 = fmaxf(l2, 0.f);
        float k4 = __expf(-l2 * cexp16);
        float k3 = k4 * k4;
        float k2 = k3 * k3;
        float k1 = k2 * k2;
        float k0 = k1 * k1;
        s += k0 + k1 + k2 + k3 + k4;
      }
    }
  }
  s = wave_sum(s);
  if (lane == 0) sm.red[wave] = s;
  __syncthreads();
  if (t == 0) {
    float ts = sm.red[0] + sm.red[1] + sm.red[2] + sm.red[3];
    int idx; float wgt;
    if (bi == bj)      { idx = (bi < 32) ? 3 : 4; wgt = 1.f; }
    else if (bj < 32)  { idx = 3; wgt = 2.f; }
    else if (bi >= 32) { idx = 4; wgt = 2.f; }
    else               { idx = 5; wgt = 2.f; }
    atomicAdd(&W[idx], wgt * ts);
  }
}

__device__ void nll_body(int bid, const float* __restrict__ pred,
                         const int* __restrict__ tgt, float* __restrict__ W,
                         SmemMain& sm) {
  const int t = threadIdx.x;
  const int i = bid * 256 + t;
  float v = pred[(size_t)i * NCLS + tgt[i]];
  v = wave_sum(v);
  if ((t & 63) == 0) sm.red[t >> 6] = v;
  __syncthreads();
  if (t == 0)
    atomicAdd(&W[0], sm.red[0] + sm.red[1] + sm.red[2] + sm.red[3]);
}

__device__ void matdiff_body(int bid, const float* __restrict__ trans,
                             float* __restrict__ W, SmemMain& sm) {
  const int t = threadIdx.x;
  const int lane = t & 63, wave = t >> 6;
  const int b = bid * 4 + wave;           // 1 item per wave, 4 waves
  const float* Tb = trans + (size_t)b * 4096;
  const int fr = lane & 15;
  const int k8 = (lane >> 4) * 8;
  bf16x8 frag[4][2];
  #pragma unroll
  for (int m = 0; m < 4; ++m) {
    #pragma unroll
    for (int kk = 0; kk < 2; ++kk) {
      const float* p = Tb + (size_t)(16 * m + fr) * 64 + kk * 32 + k8;
      float4 u0 = *(const float4*)p;
      float4 u1 = *(const float4*)(p + 4);
      bf16x8 f;
      f[0] = (short)f2bf(u0.x); f[1] = (short)f2bf(u0.y);
      f[2] = (short)f2bf(u0.z); f[3] = (short)f2bf(u0.w);
      f[4] = (short)f2bf(u1.x); f[5] = (short)f2bf(u1.y);
      f[6] = (short)f2bf(u1.z); f[7] = (short)f2bf(u1.w);
      frag[m][kk] = f;
    }
  }
  f32x4 acc[4][4];
  #pragma unroll
  for (int m = 0; m < 4; ++m)
    #pragma unroll
    for (int n = 0; n < 4; ++n) acc[m][n] = (f32x4)(0.f);
  #pragma unroll
  for (int kk = 0; kk < 2; ++kk)
    #pragma unroll
    for (int m = 0; m < 4; ++m)
      #pragma unroll
      for (int n = 0; n < 4; ++n)
        acc[m][n] = __builtin_amdgcn_mfma_f32_16x16x32_bf16(frag[m][kk], frag[n][kk],
                                                            acc[m][n], 0, 0, 0);
  float s = 0.f;
  const int crow = (lane >> 4) * 4;
  #pragma unroll
  for (int m = 0; m < 4; ++m)
    #pragma unroll
    for (int n = 0; n < 4; ++n)
      #pragma unroll
      for (int r = 0; r < 4; ++r) {
        int grow = 16 * m + crow + r;
        int gcol = 16 * n + fr;
        float g = acc[m][n][r];
        float d = (grow == gcol) ? (1.f - g) : (-g);
        s += d * d;
      }
  s = wave_sum(s);
  if (lane == 0) sm.red[wave] = sqrtf(s);
  __syncthreads();
  if (t == 0)
    atomicAdd(&W[1], sm.red[0] + sm.red[1] + sm.red[2] + sm.red[3]);
}

__global__ __launch_bounds__(256, 3) void fused_main_k(
    const float* __restrict__ pred, const int* __restrict__ tgt,
    const float* __restrict__ trans, const unsigned short* __restrict__ tot,
    float* __restrict__ W, float* __restrict__ out) {
  __shared__ SmemMain sm;
  const int blk = blockIdx.x;
  if (blk < NGRAM)             gram_body(blk, tot, W, sm);
  else if (blk < NGRAM + NNLL) nll_body(blk - NGRAM, pred, tgt, W, sm);
  else                         matdiff_body(blk - NGRAM - NNLL, trans, W, sm);

  // ticket: last of all NMAIN blocks does the final combine
  if (threadIdx.x == 0) {
    __threadfence();
    unsigned int tk = atomicAdd((unsigned int*)(W + 7), 1u);
    if (tk == NMAIN - 1) {
      __threadfence();
      float nll = -*(volatile float*)(W + 0) / (float)B_ROWS;
      float mat =  *(volatile float*)(W + 1) / (float)B_ROWS;
      float sxx =  *(volatile float*)(W + 3);
      float syy =  *(volatile float*)(W + 4);
      float smx =  *(volatile float*)(W + 5);
      float mmd = (sxx + syy - smx) / ((float)B_ROWS * (float)B_ROWS);
      out[0] = 0.1f * nll + 0.001f * mat + 0.5f * mmd;
    }
  }
}

extern "C" void kernel_launch(void* const* d_in, const int* in_sizes, int n_in,
                              void* d_out, int out_size, void* d_ws, size_t ws_size,
                              hipStream_t stream) {
  const float* pred   = (const float*)d_in[0];
  const int*   tgt    = (const int*)d_in[1];
  const float* trans  = (const float*)d_in[2];
  const float* dense  = (const float*)d_in[3];
  const float* sparse = (const float*)d_in[4];
  float* W = (float*)d_ws;
  unsigned short* tot = (unsigned short*)((char*)d_ws + WS_TOT_BYTE_OFF);
  float* out = (float*)d_out;

  init_k<<<dim3(5), dim3(256), 0, stream>>>(W);
  prep_k<<<dim3(512), dim3(256), 0, stream>>>(dense, sparse, W, tot);
  fused_main_k<<<dim3(NMAIN), dim3(256), 0, stream>>>(pred, tgt, trans, tot, W, out);
}

// Round 9
// 220.144 us; speedup vs baseline: 4.6126x; 1.8311x over previous
//
#include <hip/hip_runtime.h>
#include <math.h>

#define B_ROWS 4096
#define DIM    1024
#define NTOT   8192
#define NCLS   40
#define TILES2 32          // 8192 / 256
#define NGRAM  528         // 32*33/2 upper-tri 256^2 tiles
#define NPREP  512
#define NNLL   16          // 4096 / 256
#define NMATD  1024        // 4096 / 4
#define NPRE   (NPREP + NNLL + NMATD)   // 1552

typedef __attribute__((ext_vector_type(8))) short bf16x8;
typedef __attribute__((ext_vector_type(4))) float f32x4;

// ws layout (floats): [0]=nll_sum [1]=matdiff_sum [2]=sum_sq [3]=sxx [4]=syy
// [5]=smix(xy+yx) [6]=unused [7]=gram ticket ; [8..1032)=colsum[1024] ;
// [1032..9224)=sq[8192] ; byte 36896+ : bf16 total[8192*1024]
#define WS_TOT_BYTE_OFF 36896

#define MFMA16(d, x, y) d = __builtin_amdgcn_mfma_f32_16x16x32_bf16(x, y, d, 0, 0, 0)

__device__ __forceinline__ unsigned short f2bf(float f) {
  unsigned int u = __float_as_uint(f);
  u += 0x7fffu + ((u >> 16) & 1u);   // RNE
  return (unsigned short)(u >> 16);
}

__device__ __forceinline__ void async16(const void* g, void* l) {
  __builtin_amdgcn_global_load_lds(
      (const __attribute__((address_space(1))) unsigned int*)g,
      (__attribute__((address_space(3))) unsigned int*)l, 16, 0, 0);
}

__device__ __forceinline__ float wave_sum(float v) {
  v += __shfl_xor(v, 32);
  v += __shfl_xor(v, 16);
  v += __shfl_xor(v, 8);
  v += __shfl_xor(v, 4);
  v += __shfl_xor(v, 2);
  v += __shfl_xor(v, 1);
  return v;
}

// ---------------- fused pre: prep (512) + nll (16) + matdiff (1024) ----------

struct PreSmem {
  float colsum_l[1024];
  float red[4];
};

__device__ void prep_body(int blk, const float* __restrict__ dense,
                          const float* __restrict__ sparse,
                          float* __restrict__ W,
                          unsigned short* __restrict__ tot, PreSmem& ps) {
  float* colsum = W + 8;
  float* sq = W + 1032;
  const int t = threadIdx.x;
  const int lane = t & 63, wave = t >> 6;
  #pragma unroll
  for (int x = 0; x < 4; ++x) ps.colsum_l[t * 4 + x] = 0.f;

  float c[4][4];
  #pragma unroll
  for (int j = 0; j < 4; ++j)
    #pragma unroll
    for (int x = 0; x < 4; ++x) c[j][x] = 0.f;

  float rowtot = 0.f;
  const int rbase = blk * 16 + wave;   // 4 rows per wave, stride 4
  for (int i = 0; i < 4; ++i) {
    const int r = rbase + i * 4;
    const float* src = (r < B_ROWS) ? dense + (size_t)r * DIM
                                    : sparse + (size_t)(r - B_ROWS) * DIM;
    float sp = 0.f;
    #pragma unroll
    for (int j = 0; j < 4; ++j) {
      float4 v = ((const float4*)src)[lane + 64 * j];
      c[j][0] += v.x; c[j][1] += v.y; c[j][2] += v.z; c[j][3] += v.w;
      sp += v.x * v.x + v.y * v.y + v.z * v.z + v.w * v.w;
      ushort4 o;
      o.x = f2bf(v.x); o.y = f2bf(v.y); o.z = f2bf(v.z); o.w = f2bf(v.w);
      *(ushort4*)(tot + (size_t)r * DIM + (lane + 64 * j) * 4) = o;
    }
    sp = wave_sum(sp);
    if (lane == 0) { sq[r] = sp; rowtot += sp; }
  }
  if (lane == 0) ps.red[wave] = rowtot;

  __syncthreads();
  #pragma unroll
  for (int j = 0; j < 4; ++j)
    #pragma unroll
    for (int x = 0; x < 4; ++x)
      atomicAdd(&ps.colsum_l[4 * lane + 256 * j + x], c[j][x]);
  __syncthreads();
  #pragma unroll
  for (int x = 0; x < 4; ++x)
    atomicAdd(&colsum[t * 4 + x], ps.colsum_l[t * 4 + x]);
  if (t == 0) atomicAdd(&W[2], ps.red[0] + ps.red[1] + ps.red[2] + ps.red[3]);
}

__device__ void nll_body(int bid, const float* __restrict__ pred,
                         const int* __restrict__ tgt, float* __restrict__ W,
                         PreSmem& ps) {
  const int t = threadIdx.x;
  const int i = bid * 256 + t;
  float v = pred[(size_t)i * NCLS + tgt[i]];
  v = wave_sum(v);
  if ((t & 63) == 0) ps.red[t >> 6] = v;
  __syncthreads();
  if (t == 0)
    atomicAdd(&W[0], ps.red[0] + ps.red[1] + ps.red[2] + ps.red[3]);
}

__device__ void matdiff_body(int bid, const float* __restrict__ trans,
                             float* __restrict__ W, PreSmem& ps) {
  const int t = threadIdx.x;
  const int lane = t & 63, wave = t >> 6;
  const int b = bid * 4 + wave;           // 1 item per wave, 4 waves
  const float* Tb = trans + (size_t)b * 4096;
  const int fr = lane & 15;
  const int k8 = (lane >> 4) * 8;
  bf16x8 frag[4][2];
  #pragma unroll
  for (int m = 0; m < 4; ++m) {
    #pragma unroll
    for (int kk = 0; kk < 2; ++kk) {
      const float* p = Tb + (size_t)(16 * m + fr) * 64 + kk * 32 + k8;
      float4 u0 = *(const float4*)p;
      float4 u1 = *(const float4*)(p + 4);
      bf16x8 f;
      f[0] = (short)f2bf(u0.x); f[1] = (short)f2bf(u0.y);
      f[2] = (short)f2bf(u0.z); f[3] = (short)f2bf(u0.w);
      f[4] = (short)f2bf(u1.x); f[5] = (short)f2bf(u1.y);
      f[6] = (short)f2bf(u1.z); f[7] = (short)f2bf(u1.w);
      frag[m][kk] = f;
    }
  }
  f32x4 acc[4][4];
  #pragma unroll
  for (int m = 0; m < 4; ++m)
    #pragma unroll
    for (int n = 0; n < 4; ++n) acc[m][n] = (f32x4)(0.f);
  #pragma unroll
  for (int kk = 0; kk < 2; ++kk)
    #pragma unroll
    for (int m = 0; m < 4; ++m)
      #pragma unroll
      for (int n = 0; n < 4; ++n)
        acc[m][n] = __builtin_amdgcn_mfma_f32_16x16x32_bf16(frag[m][kk], frag[n][kk],
                                                            acc[m][n], 0, 0, 0);
  float s = 0.f;
  const int crow = (lane >> 4) * 4;
  #pragma unroll
  for (int m = 0; m < 4; ++m)
    #pragma unroll
    for (int n = 0; n < 4; ++n)
      #pragma unroll
      for (int r = 0; r < 4; ++r) {
        int grow = 16 * m + crow + r;
        int gcol = 16 * n + fr;
        float g = acc[m][n][r];
        float d = (grow == gcol) ? (1.f - g) : (-g);
        s += d * d;
      }
  s = wave_sum(s);
  if (lane == 0) ps.red[wave] = sqrtf(s);
  __syncthreads();
  if (t == 0)
    atomicAdd(&W[1], ps.red[0] + ps.red[1] + ps.red[2] + ps.red[3]);
}

__global__ __launch_bounds__(256) void fused_pre_k(
    const float* __restrict__ pred, const int* __restrict__ tgt,
    const float* __restrict__ trans, const float* __restrict__ dense,
    const float* __restrict__ sparse, float* __restrict__ W,
    unsigned short* __restrict__ tot) {
  __shared__ PreSmem ps;
  const int blk = blockIdx.x;
  if (blk < NPREP)             prep_body(blk, dense, sparse, W, tot, ps);
  else if (blk < NPREP + NNLL) nll_body(blk - NPREP, pred, tgt, W, ps);
  else                         matdiff_body(blk - NPREP - NNLL, trans, W, ps);
}

// ---------------- gram: r5 config VERBATIM (best measured: 135 us) -----------
// 256x256 tiles, 8 waves (2Mx4N), BK=32, ring-4 LDS, counted vmcnt(8),
// 2 barriers/tile, setprio on MFMA clusters.  T1 XCD chunking; T2 swizzle
// (rule #21; verified 0 conflicts, absmax 0).
__global__ __launch_bounds__(512, 2) void gram_k(const unsigned short* __restrict__ tot,
                                                 float* __restrict__ W,
                                                 float* __restrict__ out) {
  __shared__ short As[4][8192];   // [slot][256 rows x 32 k] = 16KB per slot
  __shared__ short Bs[4][8192];
  __shared__ float sqA[256], sqB[256], red[8];
  const float* sq = W + 1032;
  const float* colsum = W + 8;
  const int t = threadIdx.x;              // 0..511
  const int lane = t & 63, wave = t >> 6; // 8 waves
  const int wr = wave >> 2, wc = wave & 3;

  int p = (blockIdx.x & 7) * (NGRAM / 8) + (blockIdx.x >> 3);

  int bi = (int)((2 * TILES2 + 1 -
                  sqrtf((float)((2 * TILES2 + 1) * (2 * TILES2 + 1) - 8 * p))) * 0.5f);
  if (bi < 0) bi = 0;
  if (bi >= TILES2) bi = TILES2 - 1;
  int start = bi * (2 * TILES2 - bi + 1) / 2;
  while (p < start) { --bi; start = bi * (2 * TILES2 - bi + 1) / 2; }
  while (p >= start + (TILES2 - bi)) { start += TILES2 - bi; ++bi; }
  const int bj = bi + (p - start);

  const int r0 = t >> 2;
  const int sg = (t & 3) ^ ((r0 >> 1) & 3);
  const unsigned short* gA0 = tot + (size_t)(bi * 256 + r0) * DIM + sg * 8;
  const unsigned short* gA1 = gA0 + (size_t)128 * DIM;
  const unsigned short* gB0 = tot + (size_t)(bj * 256 + r0) * DIM + sg * 8;
  const unsigned short* gB1 = gB0 + (size_t)128 * DIM;
  const int ldo0 = t * 8, ldo1 = t * 8 + 4096;

  auto stageA = [&](int kt, short* sl) {
    const size_t ko = (size_t)kt * 32;
    async16(gA0 + ko, sl + ldo0);
    async16(gA1 + ko, sl + ldo1);
  };
  auto stageB = [&](int kt, short* sl) {
    const size_t ko = (size_t)kt * 32;
    async16(gB0 + ko, sl + ldo0);
    async16(gB1 + ko, sl + ldo1);
  };

  stageA(0, &As[0][0]); stageB(0, &Bs[0][0]);
  stageA(1, &As[1][0]); stageB(1, &Bs[1][0]);
  stageA(2, &As[2][0]); stageB(2, &Bs[2][0]);

  if (t < 256) sqA[t] = sq[bi * 256 + t];
  else         sqB[t - 256] = sq[bj * 256 + (t - 256)];
  float csp = 0.f;
  #pragma unroll
  for (int j = 0; j < 16; ++j) { float v = colsum[lane + 64 * j]; csp += v * v; }
  csp = wave_sum(csp);
  double sumdots = (double)csp;
  double sum_sq = (double)W[2];
  double sumL2 = 2.0 * (double)NTOT * sum_sq - 2.0 * sumdots;
  double bwv = sumL2 / ((double)NTOT * (double)NTOT - (double)NTOT);
  const float cexp16 = (float)(4.0 / bwv) * 0.0625f;

  f32x4 acc[8][4];
  #pragma unroll
  for (int m = 0; m < 8; ++m)
    #pragma unroll
    for (int n = 0; n < 4; ++n) acc[m][n] = (f32x4)(0.f);

  const int q = lane >> 4;
  const int fr = lane & 15;
  const int rb = (q ^ ((fr >> 1) & 3)) << 4;
  const int aoff = (wr * 128 + fr) * 64 + rb;
  const int boff = (wc * 64 + fr) * 64 + rb;

  asm volatile("s_waitcnt vmcnt(8)" ::: "memory");
  __builtin_amdgcn_s_barrier();

  for (int u = 0; u < 8; ++u) {
    #pragma unroll
    for (int j = 0; j < 4; ++j) {
      const int kt = u * 4 + j;
      const char* cA = (const char*)&As[j][0];
      const char* cB = (const char*)&Bs[j][0];
      short* stA = &As[(j + 3) & 3][0];
      short* stB = &Bs[(j + 3) & 3][0];
      const bool st = (kt < 29);

      bf16x8 a[4], b[4];

      // ---- ph0: m0-3 x n0-3 ----
      #pragma unroll
      for (int m = 0; m < 4; ++m) a[m] = *(const bf16x8*)(cA + aoff + m * 1024);
      #pragma unroll
      for (int n = 0; n < 4; ++n) b[n] = *(const bf16x8*)(cB + boff + n * 1024);
      if (st) stageA(kt + 3, stA);
      __builtin_amdgcn_s_barrier();
      asm volatile("s_waitcnt lgkmcnt(0)" ::: "memory");
      __builtin_amdgcn_s_setprio(1);
      #pragma unroll
      for (int m = 0; m < 4; ++m)
        #pragma unroll
        for (int n = 0; n < 4; ++n) MFMA16(acc[m][n], a[m], b[n]);
      __builtin_amdgcn_s_setprio(0);
      __builtin_amdgcn_s_barrier();

      // ---- ph1: m4-7 x n0-3 (b[] reused from regs) ----
      #pragma unroll
      for (int m = 0; m < 4; ++m) a[m] = *(const bf16x8*)(cA + aoff + (4 + m) * 1024);
      if (st) stageB(kt + 3, stB);
      __builtin_amdgcn_s_barrier();
      asm volatile("s_waitcnt lgkmcnt(0)" ::: "memory");
      __builtin_amdgcn_s_setprio(1);
      #pragma unroll
      for (int m = 0; m < 4; ++m)
        #pragma unroll
        for (int n = 0; n < 4; ++n) MFMA16(acc[4 + m][n], a[m], b[n]);
      __builtin_amdgcn_s_setprio(0);
      if (kt < 29)       { asm volatile("s_waitcnt vmcnt(8)" ::: "memory"); }
      else if (kt == 29) { asm volatile("s_waitcnt vmcnt(4)" ::: "memory"); }
      else if (kt == 30) { asm volatile("s_waitcnt vmcnt(0)" ::: "memory"); }
      __builtin_amdgcn_s_barrier();
    }
  }

  float s = 0.f;
  const int crow = (lane >> 4) * 4;
  #pragma unroll
  for (int m = 0; m < 8; ++m) {
    #pragma unroll
    for (int n = 0; n < 4; ++n) {
      #pragma unroll
      for (int r = 0; r < 4; ++r) {
        int il = wr * 128 + 16 * m + crow + r;
        int jl = wc * 64 + 16 * n + fr;
        float l2 = sqA[il] + sqB[jl] - 2.f * acc[m][n][r];
        l2 = fmaxf(l2, 0.f);
        float k4 = __expf(-l2 * cexp16);
        float k3 = k4 * k4;
        float k2 = k3 * k3;
        float k1 = k2 * k2;
        float k0 = k1 * k1;
        s += k0 + k1 + k2 + k3 + k4;
      }
    }
  }
  s = wave_sum(s);
  if (lane == 0) red[wave] = s;
  __syncthreads();
  if (t == 0) {
    float ts = 0.f;
    #pragma unroll
    for (int w = 0; w < 8; ++w) ts += red[w];
    int idx; float wgt;
    if (bi == bj)      { idx = (bi < 16) ? 3 : 4; wgt = 1.f; }
    else if (bj < 16)  { idx = 3; wgt = 2.f; }
    else if (bi >= 16) { idx = 4; wgt = 2.f; }
    else               { idx = 5; wgt = 2.f; }
    atomicAdd(&W[idx], wgt * ts);
    __threadfence();
    unsigned int tk = atomicAdd((unsigned int*)(W + 7), 1u);
    if (tk == NGRAM - 1) {   // last gram block: final combine
      __threadfence();
      float nll = -*(volatile float*)(W + 0) / (float)B_ROWS;
      float mat =  *(volatile float*)(W + 1) / (float)B_ROWS;
      float sxx =  *(volatile float*)(W + 3);
      float syy =  *(volatile float*)(W + 4);
      float smx =  *(volatile float*)(W + 5);
      float mmd = (sxx + syy - smx) / ((float)B_ROWS * (float)B_ROWS);
      out[0] = 0.1f * nll + 0.001f * mat + 0.5f * mmd;
    }
  }
}

extern "C" void kernel_launch(void* const* d_in, const int* in_sizes, int n_in,
                              void* d_out, int out_size, void* d_ws, size_t ws_size,
                              hipStream_t stream) {
  const float* pred   = (const float*)d_in[0];
  const int*   tgt    = (const int*)d_in[1];
  const float* trans  = (const float*)d_in[2];
  const float* dense  = (const float*)d_in[3];
  const float* sparse = (const float*)d_in[4];
  float* W = (float*)d_ws;
  unsigned short* tot = (unsigned short*)((char*)d_ws + WS_TOT_BYTE_OFF);
  float* out = (float*)d_out;

  // zero scalars + ticket + colsum (replaces init_k launch)
  hipMemsetAsync(W, 0, 1032 * sizeof(float), stream);
  fused_pre_k<<<dim3(NPRE), dim3(256), 0, stream>>>(pred, tgt, trans, dense, sparse, W, tot);
  gram_k<<<dim3(NGRAM), dim3(512), 0, stream>>>(tot, W, out);
}

// Round 10
// 185.362 us; speedup vs baseline: 5.4782x; 1.1876x over previous
//
#include <hip/hip_runtime.h>
#include <math.h>

#define B_ROWS 4096
#define DIM    1024
#define NTOT   8192
#define NCLS   40
#define TILES2 32          // 8192 / 256
#define NGRAM  528         // 32*33/2 upper-tri 256^2 tiles
#define NPREP  256
#define NNLL   16          // 4096 / 256
#define NMATD  1024        // 4096 / 4
#define NPRE   (NPREP + NNLL + NMATD)   // 1296

typedef __attribute__((ext_vector_type(8))) short bf16x8;
typedef __attribute__((ext_vector_type(4))) float f32x4;

// ws layout (floats): [0]=nll_sum [1]=matdiff_sum [2]=sum_sq [3]=sxx [4]=syy
// [5]=smix(xy+yx) [6]=unused [7]=gram ticket ; [8..1032)=colsum[1024] ;
// [1032..9224)=sq[8192] ; byte 36896+ : bf16 total[8192*1024]
#define WS_TOT_BYTE_OFF 36896

#define MFMA16(d, x, y) d = __builtin_amdgcn_mfma_f32_16x16x32_bf16(x, y, d, 0, 0, 0)

__device__ __forceinline__ unsigned short f2bf(float f) {
  unsigned int u = __float_as_uint(f);
  u += 0x7fffu + ((u >> 16) & 1u);   // RNE
  return (unsigned short)(u >> 16);
}

__device__ __forceinline__ void async16(const void* g, void* l) {
  __builtin_amdgcn_global_load_lds(
      (const __attribute__((address_space(1))) unsigned int*)g,
      (__attribute__((address_space(3))) unsigned int*)l, 16, 0, 0);
}

__device__ __forceinline__ float wave_sum(float v) {
  v += __shfl_xor(v, 32);
  v += __shfl_xor(v, 16);
  v += __shfl_xor(v, 8);
  v += __shfl_xor(v, 4);
  v += __shfl_xor(v, 2);
  v += __shfl_xor(v, 1);
  return v;
}

// ---------------- fused pre: prep (256) + nll (16) + matdiff (1024) ----------

struct PreSmem {
  float colsum_l[1024];
  float red[4];
};

__device__ void prep_body(int blk, const float* __restrict__ dense,
                          const float* __restrict__ sparse,
                          float* __restrict__ W,
                          unsigned short* __restrict__ tot, PreSmem& ps) {
  float* colsum = W + 8;
  float* sq = W + 1032;
  const int t = threadIdx.x;
  const int lane = t & 63, wave = t >> 6;
  #pragma unroll
  for (int x = 0; x < 4; ++x) ps.colsum_l[t * 4 + x] = 0.f;

  float c[4][4];
  #pragma unroll
  for (int j = 0; j < 4; ++j)
    #pragma unroll
    for (int x = 0; x < 4; ++x) c[j][x] = 0.f;

  float rowtot = 0.f;
  const int rbase = blk * 32 + wave;   // 8 rows per wave, stride 4
  for (int i = 0; i < 8; ++i) {
    const int r = rbase + i * 4;
    const float* src = (r < B_ROWS) ? dense + (size_t)r * DIM
                                    : sparse + (size_t)(r - B_ROWS) * DIM;
    float sp = 0.f;
    #pragma unroll
    for (int j = 0; j < 4; ++j) {
      float4 v = ((const float4*)src)[lane + 64 * j];
      c[j][0] += v.x; c[j][1] += v.y; c[j][2] += v.z; c[j][3] += v.w;
      sp += v.x * v.x + v.y * v.y + v.z * v.z + v.w * v.w;
      ushort4 o;
      o.x = f2bf(v.x); o.y = f2bf(v.y); o.z = f2bf(v.z); o.w = f2bf(v.w);
      *(ushort4*)(tot + (size_t)r * DIM + (lane + 64 * j) * 4) = o;
    }
    sp = wave_sum(sp);
    if (lane == 0) { sq[r] = sp; rowtot += sp; }
  }
  if (lane == 0) ps.red[wave] = rowtot;

  __syncthreads();
  #pragma unroll
  for (int j = 0; j < 4; ++j)
    #pragma unroll
    for (int x = 0; x < 4; ++x)
      atomicAdd(&ps.colsum_l[4 * lane + 256 * j + x], c[j][x]);
  __syncthreads();
  // rotated atomic walk: blocks cover the same 1024 addresses but start at
  // disjoint offsets -> same-address contention ~1-2 instead of ~#resident
  #pragma unroll
  for (int x = 0; x < 4; ++x) {
    const int g = (t * 4 + x + blk * 64) & 1023;
    atomicAdd(&colsum[g], ps.colsum_l[g]);
  }
  if (t == 0) atomicAdd(&W[2], ps.red[0] + ps.red[1] + ps.red[2] + ps.red[3]);
}

__device__ void nll_body(int bid, const float* __restrict__ pred,
                         const int* __restrict__ tgt, float* __restrict__ W,
                         PreSmem& ps) {
  const int t = threadIdx.x;
  const int i = bid * 256 + t;
  float v = pred[(size_t)i * NCLS + tgt[i]];
  v = wave_sum(v);
  if ((t & 63) == 0) ps.red[t >> 6] = v;
  __syncthreads();
  if (t == 0)
    atomicAdd(&W[0], ps.red[0] + ps.red[1] + ps.red[2] + ps.red[3]);
}

__device__ void matdiff_body(int bid, const float* __restrict__ trans,
                             float* __restrict__ W, PreSmem& ps) {
  const int t = threadIdx.x;
  const int lane = t & 63, wave = t >> 6;
  const int b = bid * 4 + wave;           // 1 item per wave, 4 waves
  const float* Tb = trans + (size_t)b * 4096;
  const int fr = lane & 15;
  const int k8 = (lane >> 4) * 8;
  bf16x8 frag[4][2];
  #pragma unroll
  for (int m = 0; m < 4; ++m) {
    #pragma unroll
    for (int kk = 0; kk < 2; ++kk) {
      const float* p = Tb + (size_t)(16 * m + fr) * 64 + kk * 32 + k8;
      float4 u0 = *(const float4*)p;
      float4 u1 = *(const float4*)(p + 4);
      bf16x8 f;
      f[0] = (short)f2bf(u0.x); f[1] = (short)f2bf(u0.y);
      f[2] = (short)f2bf(u0.z); f[3] = (short)f2bf(u0.w);
      f[4] = (short)f2bf(u1.x); f[5] = (short)f2bf(u1.y);
      f[6] = (short)f2bf(u1.z); f[7] = (short)f2bf(u1.w);
      frag[m][kk] = f;
    }
  }
  f32x4 acc[4][4];
  #pragma unroll
  for (int m = 0; m < 4; ++m)
    #pragma unroll
    for (int n = 0; n < 4; ++n) acc[m][n] = (f32x4)(0.f);
  #pragma unroll
  for (int kk = 0; kk < 2; ++kk)
    #pragma unroll
    for (int m = 0; m < 4; ++m)
      #pragma unroll
      for (int n = 0; n < 4; ++n)
        acc[m][n] = __builtin_amdgcn_mfma_f32_16x16x32_bf16(frag[m][kk], frag[n][kk],
                                                            acc[m][n], 0, 0, 0);
  float s = 0.f;
  const int crow = (lane >> 4) * 4;
  #pragma unroll
  for (int m = 0; m < 4; ++m)
    #pragma unroll
    for (int n = 0; n < 4; ++n)
      #pragma unroll
      for (int r = 0; r < 4; ++r) {
        int grow = 16 * m + crow + r;
        int gcol = 16 * n + fr;
        float g = acc[m][n][r];
        float d = (grow == gcol) ? (1.f - g) : (-g);
        s += d * d;
      }
  s = wave_sum(s);
  if (lane == 0) ps.red[wave] = sqrtf(s);
  __syncthreads();
  if (t == 0)
    atomicAdd(&W[1], ps.red[0] + ps.red[1] + ps.red[2] + ps.red[3]);
}

__global__ __launch_bounds__(256) void fused_pre_k(
    const float* __restrict__ pred, const int* __restrict__ tgt,
    const float* __restrict__ trans, const float* __restrict__ dense,
    const float* __restrict__ sparse, float* __restrict__ W,
    unsigned short* __restrict__ tot) {
  __shared__ PreSmem ps;
  const int blk = blockIdx.x;
  if (blk < NPREP)             prep_body(blk, dense, sparse, W, tot, ps);
  else if (blk < NPREP + NNLL) nll_body(blk - NPREP, pred, tgt, W, ps);
  else                         matdiff_body(blk - NPREP - NNLL, trans, W, ps);
}

// ---------------- gram: r5 config VERBATIM (135 us, reproduced 3x) -----------
// 256x256 tiles, 8 waves (2Mx4N), BK=32, ring-4 LDS, counted vmcnt(8),
// 2 barriers/tile, setprio on MFMA clusters.  T1 XCD chunking; T2 swizzle
// (rule #21; verified 0 conflicts, absmax 0).
__global__ __launch_bounds__(512, 2) void gram_k(const unsigned short* __restrict__ tot,
                                                 float* __restrict__ W,
                                                 float* __restrict__ out) {
  __shared__ short As[4][8192];   // [slot][256 rows x 32 k] = 16KB per slot
  __shared__ short Bs[4][8192];
  __shared__ float sqA[256], sqB[256], red[8];
  const float* sq = W + 1032;
  const float* colsum = W + 8;
  const int t = threadIdx.x;              // 0..511
  const int lane = t & 63, wave = t >> 6; // 8 waves
  const int wr = wave >> 2, wc = wave & 3;

  int p = (blockIdx.x & 7) * (NGRAM / 8) + (blockIdx.x >> 3);

  int bi = (int)((2 * TILES2 + 1 -
                  sqrtf((float)((2 * TILES2 + 1) * (2 * TILES2 + 1) - 8 * p))) * 0.5f);
  if (bi < 0) bi = 0;
  if (bi >= TILES2) bi = TILES2 - 1;
  int start = bi * (2 * TILES2 - bi + 1) / 2;
  while (p < start) { --bi; start = bi * (2 * TILES2 - bi + 1) / 2; }
  while (p >= start + (TILES2 - bi)) { start += TILES2 - bi; ++bi; }
  const int bj = bi + (p - start);

  const int r0 = t >> 2;
  const int sg = (t & 3) ^ ((r0 >> 1) & 3);
  const unsigned short* gA0 = tot + (size_t)(bi * 256 + r0) * DIM + sg * 8;
  const unsigned short* gA1 = gA0 + (size_t)128 * DIM;
  const unsigned short* gB0 = tot + (size_t)(bj * 256 + r0) * DIM + sg * 8;
  const unsigned short* gB1 = gB0 + (size_t)128 * DIM;
  const int ldo0 = t * 8, ldo1 = t * 8 + 4096;

  auto stageA = [&](int kt, short* sl) {
    const size_t ko = (size_t)kt * 32;
    async16(gA0 + ko, sl + ldo0);
    async16(gA1 + ko, sl + ldo1);
  };
  auto stageB = [&](int kt, short* sl) {
    const size_t ko = (size_t)kt * 32;
    async16(gB0 + ko, sl + ldo0);
    async16(gB1 + ko, sl + ldo1);
  };

  stageA(0, &As[0][0]); stageB(0, &Bs[0][0]);
  stageA(1, &As[1][0]); stageB(1, &Bs[1][0]);
  stageA(2, &As[2][0]); stageB(2, &Bs[2][0]);

  if (t < 256) sqA[t] = sq[bi * 256 + t];
  else         sqB[t - 256] = sq[bj * 256 + (t - 256)];
  float csp = 0.f;
  #pragma unroll
  for (int j = 0; j < 16; ++j) { float v = colsum[lane + 64 * j]; csp += v * v; }
  csp = wave_sum(csp);
  double sumdots = (double)csp;
  double sum_sq = (double)W[2];
  double sumL2 = 2.0 * (double)NTOT * sum_sq - 2.0 * sumdots;
  double bwv = sumL2 / ((double)NTOT * (double)NTOT - (double)NTOT);
  const float cexp16 = (float)(4.0 / bwv) * 0.0625f;

  f32x4 acc[8][4];
  #pragma unroll
  for (int m = 0; m < 8; ++m)
    #pragma unroll
    for (int n = 0; n < 4; ++n) acc[m][n] = (f32x4)(0.f);

  const int q = lane >> 4;
  const int fr = lane & 15;
  const int rb = (q ^ ((fr >> 1) & 3)) << 4;
  const int aoff = (wr * 128 + fr) * 64 + rb;
  const int boff = (wc * 64 + fr) * 64 + rb;

  asm volatile("s_waitcnt vmcnt(8)" ::: "memory");
  __builtin_amdgcn_s_barrier();

  for (int u = 0; u < 8; ++u) {
    #pragma unroll
    for (int j = 0; j < 4; ++j) {
      const int kt = u * 4 + j;
      const char* cA = (const char*)&As[j][0];
      const char* cB = (const char*)&Bs[j][0];
      short* stA = &As[(j + 3) & 3][0];
      short* stB = &Bs[(j + 3) & 3][0];
      const bool st = (kt < 29);

      bf16x8 a[4], b[4];

      // ---- ph0: m0-3 x n0-3 ----
      #pragma unroll
      for (int m = 0; m < 4; ++m) a[m] = *(const bf16x8*)(cA + aoff + m * 1024);
      #pragma unroll
      for (int n = 0; n < 4; ++n) b[n] = *(const bf16x8*)(cB + boff + n * 1024);
      if (st) stageA(kt + 3, stA);
      __builtin_amdgcn_s_barrier();
      asm volatile("s_waitcnt lgkmcnt(0)" ::: "memory");
      __builtin_amdgcn_s_setprio(1);
      #pragma unroll
      for (int m = 0; m < 4; ++m)
        #pragma unroll
        for (int n = 0; n < 4; ++n) MFMA16(acc[m][n], a[m], b[n]);
      __builtin_amdgcn_s_setprio(0);
      __builtin_amdgcn_s_barrier();

      // ---- ph1: m4-7 x n0-3 (b[] reused from regs) ----
      #pragma unroll
      for (int m = 0; m < 4; ++m) a[m] = *(const bf16x8*)(cA + aoff + (4 + m) * 1024);
      if (st) stageB(kt + 3, stB);
      __builtin_amdgcn_s_barrier();
      asm volatile("s_waitcnt lgkmcnt(0)" ::: "memory");
      __builtin_amdgcn_s_setprio(1);
      #pragma unroll
      for (int m = 0; m < 4; ++m)
        #pragma unroll
        for (int n = 0; n < 4; ++n) MFMA16(acc[4 + m][n], a[m], b[n]);
      __builtin_amdgcn_s_setprio(0);
      if (kt < 29)       { asm volatile("s_waitcnt vmcnt(8)" ::: "memory"); }
      else if (kt == 29) { asm volatile("s_waitcnt vmcnt(4)" ::: "memory"); }
      else if (kt == 30) { asm volatile("s_waitcnt vmcnt(0)" ::: "memory"); }
      __builtin_amdgcn_s_barrier();
    }
  }

  float s = 0.f;
  const int crow = (lane >> 4) * 4;
  #pragma unroll
  for (int m = 0; m < 8; ++m) {
    #pragma unroll
    for (int n = 0; n < 4; ++n) {
      #pragma unroll
      for (int r = 0; r < 4; ++r) {
        int il = wr * 128 + 16 * m + crow + r;
        int jl = wc * 64 + 16 * n + fr;
        float l2 = sqA[il] + sqB[jl] - 2.f * acc[m][n][r];
        l2 = fmaxf(l2, 0.f);
        float k4 = __expf(-l2 * cexp16);
        float k3 = k4 * k4;
        float k2 = k3 * k3;
        float k1 = k2 * k2;
        float k0 = k1 * k1;
        s += k0 + k1 + k2 + k3 + k4;
      }
    }
  }
  s = wave_sum(s);
  if (lane == 0) red[wave] = s;
  __syncthreads();
  if (t == 0) {
    float ts = 0.f;
    #pragma unroll
    for (int w = 0; w < 8; ++w) ts += red[w];
    int idx; float wgt;
    if (bi == bj)      { idx = (bi < 16) ? 3 : 4; wgt = 1.f; }
    else if (bj < 16)  { idx = 3; wgt = 2.f; }
    else if (bi >= 16) { idx = 4; wgt = 2.f; }
    else               { idx = 5; wgt = 2.f; }
    atomicAdd(&W[idx], wgt * ts);
    __threadfence();
    unsigned int tk = atomicAdd((unsigned int*)(W + 7), 1u);
    if (tk == NGRAM - 1) {   // last gram block: final combine
      __threadfence();
      float nll = -*(volatile float*)(W + 0) / (float)B_ROWS;
      float mat =  *(volatile float*)(W + 1) / (float)B_ROWS;
      float sxx =  *(volatile float*)(W + 3);
      float syy =  *(volatile float*)(W + 4);
      float smx =  *(volatile float*)(W + 5);
      float mmd = (sxx + syy - smx) / ((float)B_ROWS * (float)B_ROWS);
      out[0] = 0.1f * nll + 0.001f * mat + 0.5f * mmd;
    }
  }
}

extern "C" void kernel_launch(void* const* d_in, const int* in_sizes, int n_in,
                              void* d_out, int out_size, void* d_ws, size_t ws_size,
                              hipStream_t stream) {
  const float* pred   = (const float*)d_in[0];
  const int*   tgt    = (const int*)d_in[1];
  const float* trans  = (const float*)d_in[2];
  const float* dense  = (const float*)d_in[3];
  const float* sparse = (const float*)d_in[4];
  float* W = (float*)d_ws;
  unsigned short* tot = (unsigned short*)((char*)d_ws + WS_TOT_BYTE_OFF);
  float* out = (float*)d_out;

  // zero scalars + ticket + colsum (replaces init_k launch)
  hipMemsetAsync(W, 0, 1032 * sizeof(float), stream);
  fused_pre_k<<<dim3(NPRE), dim3(256), 0, stream>>>(pred, tgt, trans, dense, sparse, W, tot);
  gram_k<<<dim3(NGRAM), dim3(512), 0, stream>>>(tot, W, out);
}

// Round 12
// 168.628 us; speedup vs baseline: 6.0218x; 1.0992x over previous
//
#include <hip/hip_runtime.h>
#include <math.h>

#define B_ROWS 4096
#define DIM    1024
#define NTOT   8192
#define NCLS   40
#define TILES2 32          // 8192 / 256
#define NTILE  528         // 32*33/2 upper-tri 256^2 tiles
#define NQUAR  64          // last 16 tiles x 4 quarters (dispatched FIRST)
#define NFULL  512         // tiles 0..511 as full blocks
#define NMATD  512         // x8 waves = 4096 items
#define NNLL   8           // x512 threads = 4096 rows
#define NMAIN  (NQUAR + NFULL + NMATD + NNLL)   // 1096

typedef __attribute__((ext_vector_type(8))) short bf16x8;
typedef __attribute__((ext_vector_type(4))) float f32x4;

// ws layout (floats): [0]=nll_sum [1]=matdiff_sum [2]=sum_sq [3]=sxx [4]=syy
// [5]=smix(xy+yx) [6]=unused [7]=ticket ; [8..1032)=colsum[1024] ;
// [1032..9224)=sq[8192] ; byte 36896+ : bf16 total[8192*1024]
#define WS_TOT_BYTE_OFF 36896

#define MFMA16(d, x, y) d = __builtin_amdgcn_mfma_f32_16x16x32_bf16(x, y, d, 0, 0, 0)

__device__ __forceinline__ unsigned short f2bf(float f) {
  unsigned int u = __float_as_uint(f);
  u += 0x7fffu + ((u >> 16) & 1u);   // RNE
  return (unsigned short)(u >> 16);
}

__device__ __forceinline__ void async16(const void* g, void* l) {
  __builtin_amdgcn_global_load_lds(
      (const __attribute__((address_space(1))) unsigned int*)g,
      (__attribute__((address_space(3))) unsigned int*)l, 16, 0, 0);
}

__device__ __forceinline__ float wave_sum(float v) {
  v += __shfl_xor(v, 32);
  v += __shfl_xor(v, 16);
  v += __shfl_xor(v, 8);
  v += __shfl_xor(v, 4);
  v += __shfl_xor(v, 2);
  v += __shfl_xor(v, 1);
  return v;
}

// decode linear upper-tri id -> (bi, bj), bi <= bj, T=32
__device__ __forceinline__ void decode_tile(int p, int& bi_o, int& bj_o) {
  int bi = (int)((2 * TILES2 + 1 -
                  sqrtf((float)((2 * TILES2 + 1) * (2 * TILES2 + 1) - 8 * p))) * 0.5f);
  if (bi < 0) bi = 0;
  if (bi >= TILES2) bi = TILES2 - 1;
  int start = bi * (2 * TILES2 - bi + 1) / 2;
  while (p < start) { --bi; start = bi * (2 * TILES2 - bi + 1) / 2; }
  while (p >= start + (TILES2 - bi)) { start += TILES2 - bi; ++bi; }
  bi_o = bi; bj_o = bi + (p - start);
}

// ---------------- prep: 256 blocks x 256 threads (r10-verified) --------------
__global__ __launch_bounds__(256) void prep_k(const float* __restrict__ dense,
                                              const float* __restrict__ sparse,
                                              float* __restrict__ W,
                                              unsigned short* __restrict__ tot) {
  float* colsum = W + 8;
  float* sq = W + 1032;
  const int t = threadIdx.x;
  const int lane = t & 63, wave = t >> 6;
  const int blk = blockIdx.x;
  __shared__ float colsum_l[1024];
  __shared__ float red[4];
  #pragma unroll
  for (int x = 0; x < 4; ++x) colsum_l[t * 4 + x] = 0.f;

  float c[4][4];
  #pragma unroll
  for (int j = 0; j < 4; ++j)
    #pragma unroll
    for (int x = 0; x < 4; ++x) c[j][x] = 0.f;

  float rowtot = 0.f;
  const int rbase = blk * 32 + wave;   // 8 rows per wave, stride 4
  for (int i = 0; i < 8; ++i) {
    const int r = rbase + i * 4;
    const float* src = (r < B_ROWS) ? dense + (size_t)r * DIM
                                    : sparse + (size_t)(r - B_ROWS) * DIM;
    float sp = 0.f;
    #pragma unroll
    for (int j = 0; j < 4; ++j) {
      float4 v = ((const float4*)src)[lane + 64 * j];
      c[j][0] += v.x; c[j][1] += v.y; c[j][2] += v.z; c[j][3] += v.w;
      sp += v.x * v.x + v.y * v.y + v.z * v.z + v.w * v.w;
      ushort4 o;
      o.x = f2bf(v.x); o.y = f2bf(v.y); o.z = f2bf(v.z); o.w = f2bf(v.w);
      *(ushort4*)(tot + (size_t)r * DIM + (lane + 64 * j) * 4) = o;
    }
    sp = wave_sum(sp);
    if (lane == 0) { sq[r] = sp; rowtot += sp; }
  }
  if (lane == 0) red[wave] = rowtot;

  __syncthreads();
  #pragma unroll
  for (int j = 0; j < 4; ++j)
    #pragma unroll
    for (int x = 0; x < 4; ++x)
      atomicAdd(&colsum_l[4 * lane + 256 * j + x], c[j][x]);
  __syncthreads();
  // rotated atomic walk: disjoint start offsets -> low same-address contention
  #pragma unroll
  for (int x = 0; x < 4; ++x) {
    const int g = (t * 4 + x + blk * 64) & 1023;
    atomicAdd(&colsum[g], colsum_l[g]);
  }
  if (t == 0) atomicAdd(&W[2], red[0] + red[1] + red[2] + red[3]);
}

// ---------------- main: quarters (64) + fulls (512) + matdiff (512) + nll (8)

struct SmemMain {
  short A[4][8192];   // [slot][256 rows x 32 k] = 16KB per slot
  short B[4][8192];
  float sqA[256], sqB[256], red[8];
};

// full 256^2 tile: r5 body VERBATIM (135 us, reproduced 4x)
__device__ void gram_full_body(int p, const unsigned short* __restrict__ tot,
                               float* __restrict__ W, SmemMain& sm) {
  const float* sq = W + 1032;
  const float* colsum = W + 8;
  const int t = threadIdx.x;
  const int lane = t & 63, wave = t >> 6;
  const int wr = wave >> 2, wc = wave & 3;

  int bi, bj;
  decode_tile(p, bi, bj);

  const int r0 = t >> 2;
  const int sg = (t & 3) ^ ((r0 >> 1) & 3);
  const unsigned short* gA0 = tot + (size_t)(bi * 256 + r0) * DIM + sg * 8;
  const unsigned short* gA1 = gA0 + (size_t)128 * DIM;
  const unsigned short* gB0 = tot + (size_t)(bj * 256 + r0) * DIM + sg * 8;
  const unsigned short* gB1 = gB0 + (size_t)128 * DIM;
  const int ldo0 = t * 8, ldo1 = t * 8 + 4096;

  auto stageA = [&](int kt, short* sl) {
    const size_t ko = (size_t)kt * 32;
    async16(gA0 + ko, sl + ldo0);
    async16(gA1 + ko, sl + ldo1);
  };
  auto stageB = [&](int kt, short* sl) {
    const size_t ko = (size_t)kt * 32;
    async16(gB0 + ko, sl + ldo0);
    async16(gB1 + ko, sl + ldo1);
  };

  stageA(0, &sm.A[0][0]); stageB(0, &sm.B[0][0]);
  stageA(1, &sm.A[1][0]); stageB(1, &sm.B[1][0]);
  stageA(2, &sm.A[2][0]); stageB(2, &sm.B[2][0]);

  if (t < 256) sm.sqA[t] = sq[bi * 256 + t];
  else         sm.sqB[t - 256] = sq[bj * 256 + (t - 256)];
  float csp = 0.f;
  #pragma unroll
  for (int j = 0; j < 16; ++j) { float v = colsum[lane + 64 * j]; csp += v * v; }
  csp = wave_sum(csp);
  double sumdots = (double)csp;
  double sum_sq = (double)W[2];
  double sumL2 = 2.0 * (double)NTOT * sum_sq - 2.0 * sumdots;
  double bwv = sumL2 / ((double)NTOT * (double)NTOT - (double)NTOT);
  const float cexp16 = (float)(4.0 / bwv) * 0.0625f;

  f32x4 acc[8][4];
  #pragma unroll
  for (int m = 0; m < 8; ++m)
    #pragma unroll
    for (int n = 0; n < 4; ++n) acc[m][n] = (f32x4)(0.f);

  const int q = lane >> 4;
  const int fr = lane & 15;
  const int rb = (q ^ ((fr >> 1) & 3)) << 4;
  const int aoff = (wr * 128 + fr) * 64 + rb;
  const int boff = (wc * 64 + fr) * 64 + rb;

  asm volatile("s_waitcnt vmcnt(8)" ::: "memory");
  __builtin_amdgcn_s_barrier();

  for (int u = 0; u < 8; ++u) {
    #pragma unroll
    for (int j = 0; j < 4; ++j) {
      const int kt = u * 4 + j;
      const char* cA = (const char*)&sm.A[j][0];
      const char* cB = (const char*)&sm.B[j][0];
      short* stA = &sm.A[(j + 3) & 3][0];
      short* stB = &sm.B[(j + 3) & 3][0];
      const bool st = (kt < 29);

      bf16x8 a[4], b[4];

      // ---- ph0: m0-3 x n0-3 ----
      #pragma unroll
      for (int m = 0; m < 4; ++m) a[m] = *(const bf16x8*)(cA + aoff + m * 1024);
      #pragma unroll
      for (int n = 0; n < 4; ++n) b[n] = *(const bf16x8*)(cB + boff + n * 1024);
      if (st) stageA(kt + 3, stA);
      __builtin_amdgcn_s_barrier();
      asm volatile("s_waitcnt lgkmcnt(0)" ::: "memory");
      __builtin_amdgcn_s_setprio(1);
      #pragma unroll
      for (int m = 0; m < 4; ++m)
        #pragma unroll
        for (int n = 0; n < 4; ++n) MFMA16(acc[m][n], a[m], b[n]);
      __builtin_amdgcn_s_setprio(0);
      __builtin_amdgcn_s_barrier();

      // ---- ph1: m4-7 x n0-3 (b[] reused from regs) ----
      #pragma unroll
      for (int m = 0; m < 4; ++m) a[m] = *(const bf16x8*)(cA + aoff + (4 + m) * 1024);
      if (st) stageB(kt + 3, stB);
      __builtin_amdgcn_s_barrier();
      asm volatile("s_waitcnt lgkmcnt(0)" ::: "memory");
      __builtin_amdgcn_s_setprio(1);
      #pragma unroll
      for (int m = 0; m < 4; ++m)
        #pragma unroll
        for (int n = 0; n < 4; ++n) MFMA16(acc[4 + m][n], a[m], b[n]);
      __builtin_amdgcn_s_setprio(0);
      if (kt < 29)       { asm volatile("s_waitcnt vmcnt(8)" ::: "memory"); }
      else if (kt == 29) { asm volatile("s_waitcnt vmcnt(4)" ::: "memory"); }
      else if (kt == 30) { asm volatile("s_waitcnt vmcnt(0)" ::: "memory"); }
      __builtin_amdgcn_s_barrier();
    }
  }

  float s = 0.f;
  const int crow = (lane >> 4) * 4;
  #pragma unroll
  for (int m = 0; m < 8; ++m) {
    #pragma unroll
    for (int n = 0; n < 4; ++n) {
      #pragma unroll
      for (int r = 0; r < 4; ++r) {
        int il = wr * 128 + 16 * m + crow + r;
        int jl = wc * 64 + 16 * n + fr;
        float l2 = sm.sqA[il] + sm.sqB[jl] - 2.f * acc[m][n][r];
        l2 = fmaxf(l2, 0.f);
        float k4 = __expf(-l2 * cexp16);
        float k3 = k4 * k4;
        float k2 = k3 * k3;
        float k1 = k2 * k2;
        float k0 = k1 * k1;
        s += k0 + k1 + k2 + k3 + k4;
      }
    }
  }
  s = wave_sum(s);
  if (lane == 0) sm.red[wave] = s;
  __syncthreads();
  if (t == 0) {
    float ts = 0.f;
    #pragma unroll
    for (int w = 0; w < 8; ++w) ts += sm.red[w];
    int idx; float wgt;
    if (bi == bj)      { idx = (bi < 16) ? 3 : 4; wgt = 1.f; }
    else if (bj < 16)  { idx = 3; wgt = 2.f; }
    else if (bi >= 16) { idx = 4; wgt = 2.f; }
    else               { idx = 5; wgt = 2.f; }
    atomicAdd(&W[idx], wgt * ts);
  }
}

// quarter tile: 128x128 output of tile (bi,bj), K=1024.  Same ring-4 counted
// pipeline with halved panels (1 load/thread/plane; vmcnt 4/2/0 tail).
// Wave-tile 64x32: acc[4][2].  Swizzle algebra identical (fragment rows all
// == fr mod 16 -> (row>>1)&3 == (fr>>1)&3).
__device__ void gram_quarter_body(int p, int quad,
                                  const unsigned short* __restrict__ tot,
                                  float* __restrict__ W, SmemMain& sm) {
  const float* sq = W + 1032;
  const float* colsum = W + 8;
  const int t = threadIdx.x;
  const int lane = t & 63, wave = t >> 6;
  const int wr = wave >> 2, wc = wave & 3;

  int bi, bj;
  decode_tile(p, bi, bj);
  const int h = quad >> 1, v = quad & 1;
  const int rA = bi * 256 + h * 128;
  const int rB = bj * 256 + v * 128;

  const int r0 = t >> 2;              // 0..127
  const int sg = (t & 3) ^ ((r0 >> 1) & 3);
  const unsigned short* gA0 = tot + (size_t)(rA + r0) * DIM + sg * 8;
  const unsigned short* gB0 = tot + (size_t)(rB + r0) * DIM + sg * 8;
  const int ldo = t * 8;              // 512 x 16B = 8KB plane

  auto stage = [&](int kt, short* sa, short* sb) {
    const size_t ko = (size_t)kt * 32;
    async16(gA0 + ko, sa + ldo);
    async16(gB0 + ko, sb + ldo);
  };

  stage(0, &sm.A[0][0], &sm.B[0][0]);
  stage(1, &sm.A[1][0], &sm.B[1][0]);
  stage(2, &sm.A[2][0], &sm.B[2][0]);

  if (t < 128)      sm.sqA[t] = sq[rA + t];
  else if (t < 256) sm.sqB[t - 128] = sq[rB + (t - 128)];
  float csp = 0.f;
  #pragma unroll
  for (int j = 0; j < 16; ++j) { float v2 = colsum[lane + 64 * j]; csp += v2 * v2; }
  csp = wave_sum(csp);
  double sumdots = (double)csp;
  double sum_sq = (double)W[2];
  double sumL2 = 2.0 * (double)NTOT * sum_sq - 2.0 * sumdots;
  double bwv = sumL2 / ((double)NTOT * (double)NTOT - (double)NTOT);
  const float cexp16 = (float)(4.0 / bwv) * 0.0625f;

  f32x4 acc[4][2];
  #pragma unroll
  for (int m = 0; m < 4; ++m)
    #pragma unroll
    for (int n = 0; n < 2; ++n) acc[m][n] = (f32x4)(0.f);

  const int q = lane >> 4;
  const int fr = lane & 15;
  const int rb = (q ^ ((fr >> 1) & 3)) << 4;
  const int aoff = (wr * 64 + fr) * 64 + rb;   // + m*1024, m=0..3
  const int boff = (wc * 32 + fr) * 64 + rb;   // + n*1024, n=0..1

  asm volatile("s_waitcnt vmcnt(4)" ::: "memory");
  __builtin_amdgcn_s_barrier();

  for (int u = 0; u < 8; ++u) {
    #pragma unroll
    for (int j = 0; j < 4; ++j) {
      const int kt = u * 4 + j;
      const char* cA = (const char*)&sm.A[j][0];
      const char* cB = (const char*)&sm.B[j][0];
      short* stA = &sm.A[(j + 3) & 3][0];
      short* stB = &sm.B[(j + 3) & 3][0];

      bf16x8 a[4], b[2];
      #pragma unroll
      for (int m = 0; m < 4; ++m) a[m] = *(const bf16x8*)(cA + aoff + m * 1024);
      #pragma unroll
      for (int n = 0; n < 2; ++n) b[n] = *(const bf16x8*)(cB + boff + n * 1024);
      if (kt < 29) stage(kt + 3, stA, stB);
      __builtin_amdgcn_s_barrier();
      asm volatile("s_waitcnt lgkmcnt(0)" ::: "memory");
      __builtin_amdgcn_s_setprio(1);
      #pragma unroll
      for (int m = 0; m < 4; ++m)
        #pragma unroll
        for (int n = 0; n < 2; ++n) MFMA16(acc[m][n], a[m], b[n]);
      __builtin_amdgcn_s_setprio(0);
      if (kt < 29)       { asm volatile("s_waitcnt vmcnt(4)" ::: "memory"); }
      else if (kt == 29) { asm volatile("s_waitcnt vmcnt(2)" ::: "memory"); }
      else if (kt == 30) { asm volatile("s_waitcnt vmcnt(0)" ::: "memory"); }
      __builtin_amdgcn_s_barrier();
    }
  }

  float s = 0.f;
  const int crow = (lane >> 4) * 4;
  #pragma unroll
  for (int m = 0; m < 4; ++m) {
    #pragma unroll
    for (int n = 0; n < 2; ++n) {
      #pragma unroll
      for (int r = 0; r < 4; ++r) {
        int il = wr * 64 + 16 * m + crow + r;
        int jl = wc * 32 + 16 * n + fr;
        float l2 = sm.sqA[il] + sm.sqB[jl] - 2.f * acc[m][n][r];
        l2 = fmaxf(l2, 0.f);
        float k4 = __expf(-l2 * cexp16);
        float k3 = k4 * k4;
        float k2 = k3 * k3;
        float k1 = k2 * k2;
        float k0 = k1 * k1;
        s += k0 + k1 + k2 + k3 + k4;
      }
    }
  }
  s = wave_sum(s);
  if (lane == 0) sm.red[wave] = s;
  __syncthreads();
  if (t == 0) {
    float ts = 0.f;
    #pragma unroll
    for (int w = 0; w < 8; ++w) ts += sm.red[w];
    int idx; float wgt;
    if (bi == bj)      { idx = (bi < 16) ? 3 : 4; wgt = 1.f; }
    else if (bj < 16)  { idx = 3; wgt = 2.f; }
    else if (bi >= 16) { idx = 4; wgt = 2.f; }
    else               { idx = 5; wgt = 2.f; }
    atomicAdd(&W[idx], wgt * ts);
  }
}

__device__ void nll_body(int bid, const float* __restrict__ pred,
                         const int* __restrict__ tgt, float* __restrict__ W,
                         SmemMain& sm) {
  const int t = threadIdx.x;
  const int i = bid * 512 + t;
  float v = pred[(size_t)i * NCLS + tgt[i]];
  v = wave_sum(v);
  if ((t & 63) == 0) sm.red[t >> 6] = v;
  __syncthreads();
  if (t == 0) {
    float s = 0.f;
    #pragma unroll
    for (int w = 0; w < 8; ++w) s += sm.red[w];
    atomicAdd(&W[0], s);
  }
}

__device__ void matdiff_body(int bid, const float* __restrict__ trans,
                             float* __restrict__ W, SmemMain& sm) {
  const int t = threadIdx.x;
  const int lane = t & 63, wave = t >> 6;
  const int b = bid * 8 + wave;           // 1 item per wave, 8 waves, 512 blocks
  const float* Tb = trans + (size_t)b * 4096;
  const int fr = lane & 15;
  const int k8 = (lane >> 4) * 8;
  bf16x8 frag[4][2];
  #pragma unroll
  for (int m = 0; m < 4; ++m) {
    #pragma unroll
    for (int kk = 0; kk < 2; ++kk) {
      const float* p = Tb + (size_t)(16 * m + fr) * 64 + kk * 32 + k8;
      float4 u0 = *(const float4*)p;
      float4 u1 = *(const float4*)(p + 4);
      bf16x8 f;
      f[0] = (short)f2bf(u0.x); f[1] = (short)f2bf(u0.y);
      f[2] = (short)f2bf(u0.z); f[3] = (short)f2bf(u0.w);
      f[4] = (short)f2bf(u1.x); f[5] = (short)f2bf(u1.y);
      f[6] = (short)f2bf(u1.z); f[7] = (short)f2bf(u1.w);
      frag[m][kk] = f;
    }
  }
  f32x4 acc[4][4];
  #pragma unroll
  for (int m = 0; m < 4; ++m)
    #pragma unroll
    for (int n = 0; n < 4; ++n) acc[m][n] = (f32x4)(0.f);
  #pragma unroll
  for (int kk = 0; kk < 2; ++kk)
    #pragma unroll
    for (int m = 0; m < 4; ++m)
      #pragma unroll
      for (int n = 0; n < 4; ++n)
        acc[m][n] = __builtin_amdgcn_mfma_f32_16x16x32_bf16(frag[m][kk], frag[n][kk],
                                                            acc[m][n], 0, 0, 0);
  float s = 0.f;
  const int crow = (lane >> 4) * 4;
  #pragma unroll
  for (int m = 0; m < 4; ++m)
    #pragma unroll
    for (int n = 0; n < 4; ++n)
      #pragma unroll
      for (int r = 0; r < 4; ++r) {
        int grow = 16 * m + crow + r;
        int gcol = 16 * n + fr;
        float g = acc[m][n][r];
        float d = (grow == gcol) ? (1.f - g) : (-g);
        s += d * d;
      }
  s = wave_sum(s);
  if (lane == 0) sm.red[wave] = sqrtf(s);
  __syncthreads();
  if (t == 0) {
    float s8 = 0.f;
    #pragma unroll
    for (int w = 0; w < 8; ++w) s8 += sm.red[w];
    atomicAdd(&W[1], s8);
  }
}

__global__ __launch_bounds__(512, 2) void main_k(
    const float* __restrict__ pred, const int* __restrict__ tgt,
    const float* __restrict__ trans, const unsigned short* __restrict__ tot,
    float* __restrict__ W, float* __restrict__ out) {
  __shared__ SmemMain sm;
  const int blk = blockIdx.x;
  if (blk < NQUAR) {
    // quarters FIRST: pack into round 1, eliminating the 3rd-round tail
    gram_quarter_body(512 + (blk >> 2), blk & 3, tot, W, sm);
  } else if (blk < NQUAR + NFULL) {
    const int bfull = blk - NQUAR;   // XCD chunking bijective over 512
    gram_full_body((bfull & 7) * 64 + (bfull >> 3), tot, W, sm);
  } else if (blk < NQUAR + NFULL + NMATD) {
    matdiff_body(blk - NQUAR - NFULL, trans, W, sm);
  } else {
    nll_body(blk - NQUAR - NFULL - NMATD, pred, tgt, W, sm);
  }

  // ticket: last of all NMAIN blocks does the final combine
  if (threadIdx.x == 0) {
    __threadfence();
    unsigned int tk = atomicAdd((unsigned int*)(W + 7), 1u);
    if (tk == NMAIN - 1) {
      __threadfence();
      float nll = -*(volatile float*)(W + 0) / (float)B_ROWS;
      float mat =  *(volatile float*)(W + 1) / (float)B_ROWS;
      float sxx =  *(volatile float*)(W + 3);
      float syy =  *(volatile float*)(W + 4);
      float smx =  *(volatile float*)(W + 5);
      float mmd = (sxx + syy - smx) / ((float)B_ROWS * (float)B_ROWS);
      out[0] = 0.1f * nll + 0.001f * mat + 0.5f * mmd;
    }
  }
}

extern "C" void kernel_launch(void* const* d_in, const int* in_sizes, int n_in,
                              void* d_out, int out_size, void* d_ws, size_t ws_size,
                              hipStream_t stream) {
  const float* pred   = (const float*)d_in[0];
  const int*   tgt    = (const int*)d_in[1];
  const float* trans  = (const float*)d_in[2];
  const float* dense  = (const float*)d_in[3];
  const float* sparse = (const float*)d_in[4];
  float* W = (float*)d_ws;
  unsigned short* tot = (unsigned short*)((char*)d_ws + WS_TOT_BYTE_OFF);
  float* out = (float*)d_out;

  hipMemsetAsync(W, 0, 1032 * sizeof(float), stream);
  prep_k<<<dim3(256), dim3(256), 0, stream>>>(dense, sparse, W, tot);
  main_k<<<dim3(NMAIN), dim3(512), 0, stream>>>(pred, tgt, trans, tot, W, out);
}